// Round 4
// baseline (213.624 us; speedup 1.0000x reference)
//
#include <hip/hip_runtime.h>

// ---------------------------------------------------------------------------
// GAT (2-layer, dense mask) on gfx950 — R4.
// vs R3: k_att1/k_att2 restructured barrier-free: no LDS staging, MFMA B
// fragments + exp tables loaded straight from global (L2-resident), zero
// __syncthreads in the j-loop. Kills the per-chunk vmcnt(0) drain that
// pinned R2/R3 at ~60 us.
// ---------------------------------------------------------------------------

typedef __attribute__((ext_vector_type(8))) short short8;   // 8 x bf16
typedef __attribute__((ext_vector_type(4))) float f32x4;
typedef unsigned long long u64;
typedef unsigned short u16;
typedef unsigned int u32;

__device__ __forceinline__ u16 f2bf_rne(float f){
  u32 u = __float_as_uint(f);
  return (u16)((u + 0x7fffu + ((u >> 16) & 1u)) >> 16);
}

// ------------------------- K0: adj -> bitmask ------------------------------
__global__ __launch_bounds__(256) void k_adj_pack(const int* __restrict__ adj,
                                                  u64* __restrict__ bits){
  int lane = threadIdx.x & 63;
  int w0 = blockIdx.x * 4 + (threadIdx.x >> 6);       // 0..16383
  #pragma unroll
  for (int k = 0; k < 16; ++k){
    int wid = w0 + k * 16384;
    int i  = wid >> 6;
    int jg = wid & 63;
    int v = adj[(size_t)i * 4096 + (jg << 6) + lane];
    u64 m = __ballot(v != 0);
    if (lane == 0) bits[(size_t)i * 64 + jg] = m;
  }
}

// ------------------------- K1: pack x->A-layout + W->B-layout --------------
__global__ __launch_bounds__(256) void k_pack_in(const float* __restrict__ x,
                                                 const float* __restrict__ W,
                                                 u16* __restrict__ xA,
                                                 u16* __restrict__ wB){
  if (blockIdx.x < 1024){
    int tid = blockIdx.x * 256 + threadIdx.x;         // 262144
    int n = tid & 4095;
    int fg = tid >> 12;
    const float* src = x + (size_t)n * 512 + fg * 8;
    float4 v0 = ((const float4*)src)[0];
    float4 v1 = ((const float4*)src)[1];
    u32 pk[4];
    pk[0] = f2bf_rne(v0.x) | ((u32)f2bf_rne(v0.y) << 16);
    pk[1] = f2bf_rne(v0.z) | ((u32)f2bf_rne(v0.w) << 16);
    pk[2] = f2bf_rne(v1.x) | ((u32)f2bf_rne(v1.y) << 16);
    pk[3] = f2bf_rne(v1.z) | ((u32)f2bf_rne(v1.w) << 16);
    *(uint4*)(xA + ((size_t)fg * 4096 + n) * 8) = *(uint4*)pk;
  } else {
    int tid = (blockIdx.x - 1024) * 256 + threadIdx.x; // 32768
    int o  = tid & 63;
    int fg = (tid >> 6) & 63;
    int h  = tid >> 12;
    const float* src = W + ((size_t)h * 512 + fg * 8) * 64 + o;
    u32 pk[4];
    #pragma unroll
    for (int p = 0; p < 4; ++p){
      u16 lo = f2bf_rne(src[(2 * p) * 64]);
      u16 hi = f2bf_rne(src[(2 * p + 1) * 64]);
      pk[p] = lo | ((u32)hi << 16);
    }
    *(uint4*)(wB + (size_t)h * 32768 + ((size_t)fg * 64 + o) * 8) = *(uint4*)pk;
  }
}

// ------------------------- K2: Wh = x @ W[h]; fused tables + whB pack ------
__global__ __launch_bounds__(256) void k_gemm1(const u16* __restrict__ xA,
                                               const u16* __restrict__ wB,
                                               const float* __restrict__ av,
                                               u16* __restrict__ whB,
                                               float* __restrict__ e11, float* __restrict__ e102,
                                               float* __restrict__ e21, float* __restrict__ e202){
  __shared__ u16 tr[4096];                 // 64 x 64 bf16, whB sub-layout
  int h    = blockIdx.y;
  int nblk = blockIdx.x;
  int lane = threadIdx.x & 63;
  int wid  = threadIdx.x >> 6;
  int row16 = lane & 15, grp = lane >> 4;
  int n0 = nblk * 64;
  int n0w = n0 + wid * 16;
  const u16* wBh = wB + (size_t)h * 32768;
  f32x4 acc[4] = {};
  #pragma unroll 4
  for (int ks = 0; ks < 16; ++ks){
    int fgb = ks * 4 + grp;
    short8 af = *(const short8*)(xA + ((size_t)fgb * 4096 + n0w + row16) * 8);
    #pragma unroll
    for (int nt = 0; nt < 4; ++nt){
      short8 bf = *(const short8*)(wBh + ((size_t)fgb * 64 + nt * 16 + row16) * 8);
      acc[nt] = __builtin_amdgcn_mfma_f32_16x16x32_bf16(af, bf, acc[nt], 0, 0, 0);
    }
  }
  // ---- epilogue 1: score tables ----
  float a1v[4], a2v[4];
  #pragma unroll
  for (int nt = 0; nt < 4; ++nt){
    a1v[nt] = av[h * 128 + nt * 16 + row16];
    a2v[nt] = av[h * 128 + 64 + nt * 16 + row16];
  }
  #pragma unroll
  for (int r = 0; r < 4; ++r){
    float p1 = acc[0][r] * a1v[0] + acc[1][r] * a1v[1] + acc[2][r] * a1v[2] + acc[3][r] * a1v[3];
    float p2 = acc[0][r] * a2v[0] + acc[1][r] * a2v[1] + acc[2][r] * a2v[2] + acc[3][r] * a2v[3];
    #pragma unroll
    for (int d = 1; d < 16; d <<= 1){ p1 += __shfl_xor(p1, d, 64); p2 += __shfl_xor(p2, d, 64); }
    if (row16 == 0){
      int idx = h * 4096 + n0w + grp * 4 + r;
      e11[idx]  = __expf(p1); e102[idx] = __expf(0.2f * p1);
      e21[idx]  = __expf(p2); e202[idx] = __expf(0.2f * p2);
    }
  }
  // ---- epilogue 2: whB bf16 pack via LDS transpose ----
  #pragma unroll
  for (int nt = 0; nt < 4; ++nt)
    #pragma unroll
    for (int r = 0; r < 4; ++r){
      int jl = wid * 16 + grp * 4 + r;       // local row 0..63
      int o  = nt * 16 + row16;
      tr[((jl >> 3) * 64 + o) * 8 + (jl & 7)] = f2bf_rne(acc[nt][r]);
    }
  __syncthreads();
  u16* dst = whB + (size_t)h * 262144 + (size_t)n0 * 64;
  #pragma unroll
  for (int q = 0; q < 2; ++q)
    *(uint4*)(dst + (threadIdx.x * 2 + q) * 8) = *(const uint4*)(tr + (threadIdx.x * 2 + q) * 8);
}

// ------------------------- K3: layer-1 attention (barrier-free) ------------
// grid (32 iblk, 8 h, 4 split); wave = 2 A-tiles (32 i); chunk = 64 j.
// B fragments + tables loaded directly from global (whB is L2-resident).
__global__ __launch_bounds__(256) void k_att1(const u16* __restrict__ whB,
                                              const u64* __restrict__ adjbits,
                                              const float* __restrict__ e11, const float* __restrict__ e102,
                                              const float* __restrict__ e21, const float* __restrict__ e202,
                                              u16* __restrict__ pnum, float* __restrict__ pden){
  __shared__ u32 smLut[4];
  int h     = blockIdx.y;
  int iblk  = blockIdx.x;
  int split = blockIdx.z;
  int lane = threadIdx.x & 63;
  int wid  = threadIdx.x >> 6;
  int row16 = lane & 15, grp = lane >> 4;
  if (threadIdx.x < 4)
    smLut[threadIdx.x] = ((threadIdx.x & 1) ? 0xFFFFu : 0u) | ((threadIdx.x & 2) ? 0xFFFF0000u : 0u);
  __syncthreads();                          // once, for the LUT only
  int ibase = iblk * 128 + wid * 32;
  int i0 = ibase + row16, i1 = ibase + 16 + row16;
  int hoff = h * 4096;
  float f1a  = e11[hoff + i0],  f1b  = e11[hoff + i1];
  float f02a = e102[hoff + i0], f02b = e102[hoff + i1];
  const u16* whBh = whB + (size_t)h * 262144;
  int jbeg = split * 1024;

  short8 bden;                              // ones-column B frag for den
  #pragma unroll
  for (int t = 0; t < 8; ++t) bden[t] = (row16 == 0) ? (short)0x3F80 : (short)0;

  f32x4 acc[2][4] = {};
  f32x4 accden[2] = {};
  #pragma unroll 2
  for (int c = 0; c < 16; ++c){
    int j0 = jbeg + c * 64;
    u64 mrow0 = adjbits[(size_t)i0 * 64 + (j0 >> 6)];
    u64 mrow1 = adjbits[(size_t)i1 * 64 + (j0 >> 6)];
    #pragma unroll
    for (int ks = 0; ks < 2; ++ks){
      int sb = (j0 >> 3) + ks * 4 + grp;    // whB sub-block index
      const u16* bb = whBh + ((size_t)sb * 64) * 8;
      short8 bf0 = *(const short8*)(bb + (0 * 16 + row16) * 8);
      short8 bf1 = *(const short8*)(bb + (1 * 16 + row16) * 8);
      short8 bf2 = *(const short8*)(bb + (2 * 16 + row16) * 8);
      short8 bf3 = *(const short8*)(bb + (3 * 16 + row16) * 8);
      const float* t1 = e21  + hoff + j0 + ks * 32 + grp * 8;
      const float* t2 = e202 + hoff + j0 + ks * 32 + grp * 8;
      float4 eA = *(const float4*)t1;
      float4 eB = *(const float4*)(t1 + 4);
      float4 gA = *(const float4*)t2;
      float4 gB = *(const float4*)(t2 + 4);
      float e1v[8] = {eA.x, eA.y, eA.z, eA.w, eB.x, eB.y, eB.z, eB.w};
      float e2v[8] = {gA.x, gA.y, gA.z, gA.w, gB.x, gB.y, gB.z, gB.w};
      #pragma unroll
      for (int it = 0; it < 2; ++it){
        u64 mrow = it ? mrow1 : mrow0;
        float f1 = it ? f1b : f1a;
        float f02 = it ? f02b : f02a;
        u32 mb = ((u32)(mrow >> (ks * 32)) >> (grp * 8)) & 0xffu;
        u32 pk[4];
        #pragma unroll
        for (int t2i = 0; t2i < 4; ++t2i){
          float w0 = fmaxf(f1 * e1v[2 * t2i],     f02 * e2v[2 * t2i]);
          float w1 = fmaxf(f1 * e1v[2 * t2i + 1], f02 * e2v[2 * t2i + 1]);
          u32 p = __builtin_amdgcn_perm(__float_as_uint(w1), __float_as_uint(w0), 0x07060302u);
          pk[t2i] = p & smLut[(mb >> (2 * t2i)) & 3u];
        }
        short8 af = *(short8*)pk;
        acc[it][0] = __builtin_amdgcn_mfma_f32_16x16x32_bf16(af, bf0, acc[it][0], 0, 0, 0);
        acc[it][1] = __builtin_amdgcn_mfma_f32_16x16x32_bf16(af, bf1, acc[it][1], 0, 0, 0);
        acc[it][2] = __builtin_amdgcn_mfma_f32_16x16x32_bf16(af, bf2, acc[it][2], 0, 0, 0);
        acc[it][3] = __builtin_amdgcn_mfma_f32_16x16x32_bf16(af, bf3, acc[it][3], 0, 0, 0);
        accden[it] = __builtin_amdgcn_mfma_f32_16x16x32_bf16(af, bden, accden[it], 0, 0, 0);
      }
    }
  }

  #pragma unroll
  for (int it = 0; it < 2; ++it){
    #pragma unroll
    for (int r = 0; r < 4; ++r){
      int n = ibase + it * 16 + grp * 4 + r;
      if (row16 == 0)
        pden[((size_t)split * 8 + h) * 4096 + n] = accden[it][r];
      u16* dst = pnum + ((size_t)split * 4096 + n) * 512 + h * 64 + row16;
      #pragma unroll
      for (int nt = 0; nt < 4; ++nt)
        dst[nt * 16] = f2bf_rne(acc[it][nt][r]);
    }
  }
}

// ------------------------- K5: combine + Who=h@Wout + layer-2 tables -------
__global__ __launch_bounds__(256) void k_gemm2(const u16* __restrict__ pnum,
                                               const float* __restrict__ pden,
                                               const float* __restrict__ Wout,
                                               const float* __restrict__ aout,
                                               u16* __restrict__ whoB,
                                               float* __restrict__ e11o, float* __restrict__ e102o,
                                               float* __restrict__ e21o, float* __restrict__ e202o){
  __shared__ float Wl[8192];                  // 512 x 16
  __shared__ float hrow[16 * 516];            // combined+elu rows, padded stride
  __shared__ float sden[128];                 // den[h][n]
  int n0 = blockIdx.x * 16;
  for (int t = threadIdx.x; t < 8192; t += 256) Wl[t] = Wout[t];
  if (threadIdx.x < 128){
    int hh = threadIdx.x >> 4, nn = threadIdx.x & 15;
    float d = 0.f;
    #pragma unroll
    for (int s = 0; s < 4; ++s) d += pden[((size_t)s * 8 + hh) * 4096 + n0 + nn];
    sden[threadIdx.x] = d;
  }
  __syncthreads();
  {
    int nn = threadIdx.x >> 4;                // row 0..15
    int fc = threadIdx.x & 15;                // 32-f chunk
    int f0 = fc * 32;
    int hh = fc >> 1;
    float dinv = 1.f / sden[hh * 16 + nn];
    float v[32];
    #pragma unroll
    for (int k = 0; k < 32; ++k) v[k] = 0.f;
    #pragma unroll
    for (int s = 0; s < 4; ++s){
      const u16* p = pnum + ((size_t)s * 4096 + n0 + nn) * 512 + f0;
      #pragma unroll
      for (int q = 0; q < 4; ++q){
        uint4 raw = *(const uint4*)(p + q * 8);
        u32 rw[4] = {raw.x, raw.y, raw.z, raw.w};
        #pragma unroll
        for (int d2 = 0; d2 < 4; ++d2){
          v[q * 8 + d2 * 2]     += __uint_as_float(rw[d2] << 16);
          v[q * 8 + d2 * 2 + 1] += __uint_as_float(rw[d2] & 0xffff0000u);
        }
      }
    }
    #pragma unroll
    for (int k = 0; k < 32; ++k){
      float val = v[k] * dinv;
      val = val > 0.f ? val : (__expf(val) - 1.f);
      hrow[nn * 516 + f0 + k] = val;
    }
  }
  __syncthreads();
  int c  = threadIdx.x & 15;
  int rl = threadIdx.x >> 4;                  // 0..15
  int n = n0 + rl;
  const float4* hr = (const float4*)(hrow + rl * 516);
  float acc = 0.f;
  #pragma unroll 8
  for (int f4 = 0; f4 < 128; ++f4){
    float4 hv = hr[f4];
    int f = f4 * 4;
    acc += hv.x * Wl[f * 16 + c] + hv.y * Wl[(f + 1) * 16 + c]
         + hv.z * Wl[(f + 2) * 16 + c] + hv.w * Wl[(f + 3) * 16 + c];
  }
  whoB[((size_t)(n >> 3) * 16 + c) * 8 + (n & 7)] = f2bf_rne(acc);
  float p1 = acc * aout[c], p2 = acc * aout[16 + c];
  #pragma unroll
  for (int d = 1; d < 16; d <<= 1){ p1 += __shfl_xor(p1, d, 64); p2 += __shfl_xor(p2, d, 64); }
  if (c == 0){
    e11o[n] = __expf(p1); e102o[n] = __expf(0.2f * p1);
    e21o[n] = __expf(p2); e202o[n] = __expf(0.2f * p2);
  }
}

// ------------------------- K6: layer-2 attention (barrier-free) ------------
__global__ __launch_bounds__(256) void k_att2(const u16* __restrict__ whoB,
                                              const u64* __restrict__ adjbits,
                                              const float* __restrict__ e11o, const float* __restrict__ e102o,
                                              const float* __restrict__ e21o, const float* __restrict__ e202o,
                                              float* __restrict__ pnum, float* __restrict__ pden){
  __shared__ u32 smLut[4];
  int iblk  = blockIdx.x;
  int split = blockIdx.y;                     // 0..15
  int lane = threadIdx.x & 63;
  int wid  = threadIdx.x >> 6;
  int row16 = lane & 15, grp = lane >> 4;
  if (threadIdx.x < 4)
    smLut[threadIdx.x] = ((threadIdx.x & 1) ? 0xFFFFu : 0u) | ((threadIdx.x & 2) ? 0xFFFF0000u : 0u);
  __syncthreads();
  int i = iblk * 64 + wid * 16 + row16;
  float f1  = e11o[i];
  float f02 = e102o[i];
  int jbeg = split * 256;
  short8 bden;
  #pragma unroll
  for (int t = 0; t < 8; ++t) bden[t] = (row16 == 0) ? (short)0x3F80 : (short)0;

  f32x4 acc = {};
  f32x4 accden = {};
  #pragma unroll
  for (int c = 0; c < 4; ++c){
    int j0 = jbeg + c * 64;
    u64 mrow = adjbits[(size_t)i * 64 + (j0 >> 6)];
    #pragma unroll
    for (int ks = 0; ks < 2; ++ks){
      int sb = (j0 >> 3) + ks * 4 + grp;
      short8 bf = *(const short8*)(whoB + ((size_t)sb * 16 + row16) * 8);
      const float* t1 = e21o  + j0 + ks * 32 + grp * 8;
      const float* t2 = e202o + j0 + ks * 32 + grp * 8;
      float4 eA = *(const float4*)t1;
      float4 eB = *(const float4*)(t1 + 4);
      float4 gA = *(const float4*)t2;
      float4 gB = *(const float4*)(t2 + 4);
      float e1v[8] = {eA.x, eA.y, eA.z, eA.w, eB.x, eB.y, eB.z, eB.w};
      float e2v[8] = {gA.x, gA.y, gA.z, gA.w, gB.x, gB.y, gB.z, gB.w};
      u32 mb = ((u32)(mrow >> (ks * 32)) >> (grp * 8)) & 0xffu;
      u32 pk[4];
      #pragma unroll
      for (int t2i = 0; t2i < 4; ++t2i){
        float w0 = fmaxf(f1 * e1v[2 * t2i],     f02 * e2v[2 * t2i]);
        float w1 = fmaxf(f1 * e1v[2 * t2i + 1], f02 * e2v[2 * t2i + 1]);
        u32 p = __builtin_amdgcn_perm(__float_as_uint(w1), __float_as_uint(w0), 0x07060302u);
        pk[t2i] = p & smLut[(mb >> (2 * t2i)) & 3u];
      }
      short8 af = *(short8*)pk;
      acc    = __builtin_amdgcn_mfma_f32_16x16x32_bf16(af, bf, acc, 0, 0, 0);
      accden = __builtin_amdgcn_mfma_f32_16x16x32_bf16(af, bden, accden, 0, 0, 0);
    }
  }
  #pragma unroll
  for (int r = 0; r < 4; ++r){
    int n = iblk * 64 + wid * 16 + grp * 4 + r;
    if (row16 == 0)
      pden[(size_t)n * 16 + split] = accden[r];
    pnum[((size_t)n * 16 + split) * 16 + row16] = acc[r];
  }
}

// ------------------------- K7: combine + elu + log_softmax -----------------
__global__ __launch_bounds__(256) void k_final(const float* __restrict__ pnum,
                                               const float* __restrict__ pden,
                                               float* __restrict__ out){
  int tid = blockIdx.x * 256 + threadIdx.x;   // 65536
  int c = tid & 15;
  int n = tid >> 4;
  float num = 0.f, den = 0.f;
  #pragma unroll
  for (int s = 0; s < 16; ++s){
    num += pnum[((size_t)n * 16 + s) * 16 + c];
    den += pden[(size_t)n * 16 + s];
  }
  float v = num / den;
  v = v > 0.f ? v : (__expf(v) - 1.f);
  float m = v;
  #pragma unroll
  for (int d = 1; d < 16; d <<= 1) m = fmaxf(m, __shfl_xor(m, d, 64));
  float es = __expf(v - m), ss = es;
  #pragma unroll
  for (int d = 1; d < 16; d <<= 1) ss += __shfl_xor(ss, d, 64);
  out[(size_t)n * 16 + c] = v - m - __logf(ss);
}

// ---------------------------------------------------------------------------
extern "C" void kernel_launch(void* const* d_in, const int* in_sizes, int n_in,
                              void* d_out, int out_size, void* d_ws, size_t ws_size,
                              hipStream_t stream){
  (void)in_sizes; (void)n_in; (void)out_size; (void)ws_size;
  const float* x    = (const float*)d_in[0];
  const int*   adj  = (const int*)d_in[1];
  const float* W    = (const float*)d_in[2];
  const float* av   = (const float*)d_in[3];
  const float* Wout = (const float*)d_in[4];
  const float* aout = (const float*)d_in[5];
  float* out = (float*)d_out;
  char* ws = (char*)d_ws;

  // --- persistent ---
  u64*  adjbits = (u64*)(ws + 0x0000000);        // 2 MB
  u16*  whB     = (u16*)(ws + 0x0200000);        // 4 MB
  float* e11    = (float*)(ws + 0x0600000);      // 4 x 128 KB exp tables
  float* e102   = (float*)(ws + 0x0620000);
  float* e21    = (float*)(ws + 0x0640000);
  float* e202   = (float*)(ws + 0x0660000);
  // --- 16 MB overlap region [0x680000, 0x1680000) ---
  u16*  xA    = (u16*)(ws + 0x0680000);          // early (dead before k_att1)
  u16*  wB    = (u16*)(ws + 0x0A80000);
  u16*  pnum1 = (u16*)(ws + 0x0680000);          // late
  // --- late persistent ---
  float* pden1 = (float*)(ws + 0x1680000);       // 512 KB
  u16*  whoB   = (u16*)(ws + 0x1700000);         // 128 KB
  float* e11o  = (float*)(ws + 0x1720000);       // 4 x 16 KB
  float* e102o = (float*)(ws + 0x1724000);
  float* e21o  = (float*)(ws + 0x1728000);
  float* e202o = (float*)(ws + 0x172C000);
  float* pnum2 = (float*)(ws + 0x1730000);       // 4 MB
  float* pden2 = (float*)(ws + 0x1B30000);       // 256 KB

  k_adj_pack<<<dim3(4096), dim3(256), 0, stream>>>(adj, adjbits);
  k_pack_in<<<dim3(1152), dim3(256), 0, stream>>>(x, W, xA, wB);
  k_gemm1<<<dim3(64, 8), dim3(256), 0, stream>>>(xA, wB, av, whB, e11, e102, e21, e202);
  k_att1<<<dim3(32, 8, 4), dim3(256), 0, stream>>>(whB, adjbits, e11, e102, e21, e202, pnum1, pden1);
  k_gemm2<<<dim3(256), dim3(256), 0, stream>>>(pnum1, pden1, Wout, aout, whoB, e11o, e102o, e21o, e202o);
  k_att2<<<dim3(64, 16), dim3(256), 0, stream>>>(whoB, adjbits, e11o, e102o, e21o, e202o, pnum2, pden2);
  k_final<<<dim3(256), dim3(256), 0, stream>>>(pnum2, pden2, out);
}